// Round 14
// baseline (265.839 us; speedup 1.0000x reference)
//
#include <hip/hip_runtime.h>
#include <stdint.h>

#define HH 4096
#define WW 4096
#define NPIX (HH * WW)
#define NBINS 8192
#define NFRAG 64
#define FRAG_PIX (512 * 512)   // 2^18
#define WPR 64                 // u64 words per row (4096/64)
#define NWORDS (HH * WPR)      // 262144
#define CAP 4096               // per-fragment critical-band capacity
#define LCAP 2048              // per-block LDS match buffer

// Reference stop conditions (integer-exact):
//   phase0 stop: cnt >= 31458 <=> th < V_HI,  V_HI = v_sorted[230686]
//   phase1 stop: cnt <= 20971 <=> th >= V_LO, V_LO = v_sorted[241172]
#define RANK_HI 230686u
#define RANK_LO 241172u

typedef unsigned long long u64;

__device__ __forceinline__ int bin_of(float v) {
  int b = (int)(v * 8192.0f);   // monotone f32 map
  if (b < 0) b = 0;
  if (b > NBINS - 1) b = NBINS - 1;
  return b;
}

// spread 16 bits so bit i lands at position 4i
__device__ __forceinline__ u64 spread4(u64 x) {
  x &= 0xFFFFull;
  x = (x | (x << 24)) & 0x000000FF000000FFull;
  x = (x | (x << 12)) & 0x000F000F000F000Full;
  x = (x | (x << 6))  & 0x0303030303030303ull;
  x = (x | (x << 3))  & 0x1111111111111111ull;
  return x;
}

// ---------------------------------------------------------------------------
// VERIFIED bit-exact blur tree (numpy pairwise_sum n=25 over materialized
// (windows*k), row-major taps, OOB -> exact 0). DO NOT TOUCH.
// ---------------------------------------------------------------------------
__device__ __forceinline__ float blur_tree(const float rowbuf[5][8], int e) {
  const float K = (float)(1.0 / 25.0);
  float p[25];
#pragma unroll
  for (int i = 0; i < 25; ++i) {
    p[i] = __fmul_rn(rowbuf[i / 5][e + (i % 5)], K);
  }
  float r0 = __fadd_rn(__fadd_rn(p[0], p[8]),  p[16]);
  float r1 = __fadd_rn(__fadd_rn(p[1], p[9]),  p[17]);
  float r2 = __fadd_rn(__fadd_rn(p[2], p[10]), p[18]);
  float r3 = __fadd_rn(__fadd_rn(p[3], p[11]), p[19]);
  float r4 = __fadd_rn(__fadd_rn(p[4], p[12]), p[20]);
  float r5 = __fadd_rn(__fadd_rn(p[5], p[13]), p[21]);
  float r6 = __fadd_rn(__fadd_rn(p[6], p[14]), p[22]);
  float r7 = __fadd_rn(__fadd_rn(p[7], p[15]), p[23]);
  float res = __fadd_rn(
      __fadd_rn(__fadd_rn(r0, r1), __fadd_rn(r2, r3)),
      __fadd_rn(__fadd_rn(r4, r5), __fadd_rn(r6, r7)));
  return __fadd_rn(res, p[24]);
}

// ---------------------------------------------------------------------------
// 1) FUSED blur + histogram, LDS-STAGED: each block stages its 16-row slice
//    (+2 halo rows, +4/+8 col halo) into LDS with one batched coalesced
//    sweep, computes the bit-exact blur from aligned LDS float4 reads
//    (2-way bank = free), then REUSES the staging LDS as the 8192-bin
//    histogram (res values live in 16 regs across the phase switch).
//    2048 blocks (64 frags x 32 slices), 512 threads.
//    Staging zeros for OOB reproduce the old OOB->0 path -> bit-exact.
// ---------------------------------------------------------------------------
#define SROWS 20
#define SCOLS 524            // 131 float4s; row stride multiple of 4
__global__ void __launch_bounds__(512)
blur_hist_kernel(const float* __restrict__ x,
                 float* __restrict__ out,
                 uint32_t* __restrict__ hist) {
  __shared__ float smem[SROWS * SCOLS];   // 41.9 KB; aliased as hist later
  int tid = threadIdx.x;
  int f = blockIdx.x >> 5;
  int s = blockIdx.x & 31;
  int row0 = (f >> 3) * 512 + s * 16;
  int col0 = (f & 7) * 512;

  // ---- stage: rows row0-2 .. row0+17, cols col0-4 .. col0+519 ----
  for (int idx = tid; idx < SROWS * 131; idx += 512) {
    int r = idx / 131;
    int c4 = idx - r * 131;
    int gy = row0 - 2 + r;
    int gcol = col0 - 4 + c4 * 4;
    float4 val = make_float4(0.f, 0.f, 0.f, 0.f);
    if ((unsigned)gy < (unsigned)HH) {
      if (gcol >= 0 && gcol + 4 <= WW) {
        val = *(const float4*)(x + (size_t)gy * WW + gcol);
      } else {
        float tmp[4];
#pragma unroll
        for (int j = 0; j < 4; ++j) {
          int xx = gcol + j;
          tmp[j] = ((unsigned)xx < (unsigned)WW) ? x[(size_t)gy * WW + xx] : 0.0f;
        }
        val = make_float4(tmp[0], tmp[1], tmp[2], tmp[3]);
      }
    }
    *(float4*)(smem + r * SCOLS + c4 * 4) = val;
  }
  __syncthreads();

  // ---- compute: one 4x4 patch per thread, windows read from LDS ----
  int pr = tid >> 7;            // 0..3
  int pc = tid & 127;           // 0..127
  int py = row0 + pr * 4;
  int px = col0 + pc * 4;
  int sc = pc * 4;              // window cols sc+2..sc+9 -> f4 at sc,sc+4,sc+8
  float res[16];
#pragma unroll
  for (int orow = 0; orow < 4; ++orow) {
    float w[5][8];
#pragma unroll
    for (int r = 0; r < 5; ++r) {
      int sr = pr * 4 + orow + r;     // staging row (py+orow-2+r)-(row0-2)
      const float* rp = smem + sr * SCOLS + sc;
      float4 a = *(const float4*)(rp);
      float4 b = *(const float4*)(rp + 4);
      float4 c = *(const float4*)(rp + 8);
      w[r][0] = a.z; w[r][1] = a.w;
      w[r][2] = b.x; w[r][3] = b.y; w[r][4] = b.z; w[r][5] = b.w;
      w[r][6] = c.x; w[r][7] = c.y;
    }
    float4 o4;
    o4.x = blur_tree(w, 0);
    o4.y = blur_tree(w, 1);
    o4.z = blur_tree(w, 2);
    o4.w = blur_tree(w, 3);
    *(float4*)(out + (size_t)(py + orow) * WW + px) = o4;
    res[orow * 4 + 0] = o4.x;
    res[orow * 4 + 1] = o4.y;
    res[orow * 4 + 2] = o4.z;
    res[orow * 4 + 3] = o4.w;
  }
  __syncthreads();

  // ---- histogram: reuse staging LDS as lh[8192] ----
  uint32_t* lh = (uint32_t*)smem;
  for (int i = tid; i < NBINS; i += 512) lh[i] = 0u;
  __syncthreads();
#pragma unroll
  for (int k = 0; k < 16; ++k) atomicAdd(&lh[bin_of(res[k])], 1u);
  __syncthreads();
  uint32_t* hf = hist + f * NBINS;
  int start = ((s << 8) + tid) & (NBINS - 1);   // 32 siblings staggered 256
  for (int ii = 0; ii < NBINS; ii += 512) {
    int i = (start + ii) & (NBINS - 1);
    uint32_t c = lh[i];
    if (c) atomicAdd(&hf[i], c);
  }
}

// ---------------------------------------------------------------------------
// 2) FUSED findcrit + gather (R10-verified): each of 1024 blocks redundantly
//    recomputes its fragment's critical bins, then atomic-privatized gather.
// ---------------------------------------------------------------------------
__global__ void __launch_bounds__(256)
findcrit_gather_kernel(const float* __restrict__ blur,
                       const uint32_t* __restrict__ hist,
                       int4* __restrict__ bins4,
                       float* __restrict__ band,
                       uint32_t* __restrict__ bandcnt) {
  __shared__ uint32_t segsum[256];
  __shared__ uint32_t segoff[256];
  __shared__ int4 sres;
  __shared__ float lval[LCAP];
  __shared__ uint32_t lcnt, gbase;
  int f = blockIdx.x >> 4;
  int s = blockIdx.x & 15;
  int tid = threadIdx.x;

  // --- findcrit (redundant per sibling block) ---
  const uint32_t* hf = hist + f * NBINS;
  int base = tid * 32;
  uint32_t h32[32];
  uint32_t sum = 0;
  for (int i = 0; i < 32; ++i) { h32[i] = hf[base + i]; sum += h32[i]; }
  segsum[tid] = sum;
  __syncthreads();
  if (tid == 0) {
    uint32_t a = 0;
    for (int i = 0; i < 256; ++i) { segoff[i] = a; a += segsum[i]; }
  }
  __syncthreads();
  uint32_t st = segoff[tid];
  uint32_t en = st + segsum[tid];
  if (st <= RANK_HI && RANK_HI < en) {
    uint32_t a = st;
    for (int i = 0; i < 32; ++i) {
      uint32_t nx = a + h32[i];
      if (RANK_HI < nx) { sres.x = base + i; sres.z = (int)(RANK_HI - a); break; }
      a = nx;
    }
  }
  if (st <= RANK_LO && RANK_LO < en) {
    uint32_t a = st;
    for (int i = 0; i < 32; ++i) {
      uint32_t nx = a + h32[i];
      if (RANK_LO < nx) { sres.y = base + i; sres.w = (int)(RANK_LO - a); break; }
      a = nx;
    }
  }
  if (tid == 0) lcnt = 0;
  __syncthreads();
  if (s == 0 && tid == 0) bins4[f] = sres;   // publish for select
  int4 info = sres;

  // --- gather (atomic-privatized) ---
  int row0 = (f >> 3) * 512 + s * 32;
  int col0 = (f & 7) * 512;
  for (int it = tid; it < 32 * 128; it += 256) {
    int rr = it >> 7, c4 = it & 127;
    float4 v = *(const float4*)(blur + (size_t)(row0 + rr) * WW + col0 + c4 * 4);
    float vv[4] = {v.x, v.y, v.z, v.w};
#pragma unroll
    for (int e = 0; e < 4; ++e) {
      int b = bin_of(vv[e]);
      if (b == info.x || b == info.y) {
        uint32_t p = atomicAdd(&lcnt, 1u);
        if (p < LCAP) lval[p] = vv[e];
        else {   // overflow fallback (never for expected data)
          uint32_t pos = atomicAdd(&bandcnt[f], 1u);
          if (pos < CAP) band[(size_t)f * CAP + pos] = vv[e];
        }
      }
    }
  }
  __syncthreads();
  uint32_t n = lcnt < LCAP ? lcnt : LCAP;
  if (tid == 0) gbase = atomicAdd(&bandcnt[f], n);
  __syncthreads();
  uint32_t bse = gbase;
  for (uint32_t i = tid; i < n; i += 256) {
    uint32_t pos = bse + i;
    if (pos < CAP) band[(size_t)f * CAP + pos] = lval[i];
  }
}

// ---------------------------------------------------------------------------
// 3) FUSED select + walk (R12-verified). Exact 8-bit radix select with a
//    block-parallel Hillis-Steele scan over the 256 bins + predicate pick.
//    Walk runs in the last-finishing block (R10-verified pattern).
// ---------------------------------------------------------------------------
__global__ void __launch_bounds__(256)
select_walk_kernel(const float* __restrict__ band,
                   const uint32_t* __restrict__ bandcnt,
                   const int4* __restrict__ bins4,
                   float2* __restrict__ vhl,
                   uint32_t* __restrict__ done,
                   float* __restrict__ th_out) {
  __shared__ uint32_t wv[CAP];       // float bits
  __shared__ uint32_t hist8[256];
  __shared__ uint32_t scan[256];
  __shared__ uint32_t resbits[2];
  __shared__ int kcur;
  __shared__ uint32_t pref;
  __shared__ uint32_t ticket;
  int f = blockIdx.x;
  int tid = threadIdx.x;
  int n = (int)bandcnt[f];
  if (n > CAP) n = CAP;
  for (int i = tid; i < n; i += 256)
    wv[i] = __float_as_uint(band[(size_t)f * CAP + i]);
  __syncthreads();
  int4 info = bins4[f];
#pragma unroll
  for (int sel = 0; sel < 2; ++sel) {
    int tb = sel ? info.y : info.x;
    int ktgt = sel ? info.w : info.z;
    if (tid == 0) { kcur = ktgt; pref = 0u; }
    __syncthreads();
    for (int pass = 0; pass < 4; ++pass) {
      int shift = 24 - pass * 8;
      uint32_t mhi = (pass == 0) ? 0u : (0xFFFFFFFFu << (shift + 8));
      uint32_t want = pref;            // read state (post-barrier)
      uint32_t kk = (uint32_t)kcur;
      hist8[tid] = 0u;
      __syncthreads();
      for (int i = tid; i < n; i += 256) {
        uint32_t b = wv[i];
        if (bin_of(__uint_as_float(b)) != tb) continue;
        if ((b & mhi) != want) continue;
        atomicAdd(&hist8[(b >> shift) & 255], 1u);
      }
      __syncthreads();
      // block-parallel inclusive scan over 256 bins (Hillis-Steele)
      uint32_t v = hist8[tid];
      scan[tid] = v;
      __syncthreads();
#pragma unroll
      for (int off = 1; off < 256; off <<= 1) {
        uint32_t t = (tid >= off) ? scan[tid - off] : 0u;
        __syncthreads();
        scan[tid] += t;
        __syncthreads();
      }
      uint32_t inc = scan[tid];
      uint32_t exc = inc - v;
      if (v && kk >= exc && kk < inc) {   // unique winner
        kcur = (int)(kk - exc);
        pref = want | ((uint32_t)tid << shift);
      }
      __syncthreads();
    }
    if (tid == 0) resbits[sel] = pref;
    __syncthreads();
  }
  if (tid == 0)
    vhl[f] = make_float2(__uint_as_float(resbits[0]), __uint_as_float(resbits[1]));
  __threadfence();
  if (tid == 0) ticket = atomicAdd(done, 1u);
  __syncthreads();
  if (ticket == NFRAG - 1) {      // last finishing block runs the walk
    __threadfence();
    if (tid < 64) {
      int lane = tid;
      float2 mine = vhl[lane];    // lane f holds fragment f's (V_HI, V_LO)
      float th = 0.5f;            // TH1_INIT
      for (int ff = 0; ff < NFRAG; ++ff) {
        float VH = __shfl(mine.x, ff);
        float VL = __shfl(mine.y, ff);
        // phase 0: while th >= VH: th -= 0.0005
        while (th >= VH) {
#pragma unroll
          for (int i = 0; i < 16; ++i) {
            float t2 = __fadd_rn(th, -0.0005f);
            th = (th >= VH) ? t2 : th;
          }
        }
        // phase 1: while th < VL: th += 0.0005
        while (th < VL) {
#pragma unroll
          for (int i = 0; i < 16; ++i) {
            float t2 = __fadd_rn(th, 0.0005f);
            th = (th < VL) ? t2 : th;
          }
        }
        if (lane == 0) th_out[ff] = th;
      }
    }
  }
}

// ---------------------------------------------------------------------------
// 4) mask + bit-pack — fragment-slice blocks; th[f] wave-uniform scalar.
// ---------------------------------------------------------------------------
__global__ void __launch_bounds__(256)
mask_pack_kernel(const float* __restrict__ blur,
                 const float* __restrict__ th,
                 u64* __restrict__ pk) {
  int f = blockIdx.x >> 4;
  int s = blockIdx.x & 15;
  int tid = threadIdx.x;
  int lane = tid & 63;
  int row0 = (f >> 3) * 512 + s * 32;
  int col0 = (f & 7) * 512;
  float tf = th[f];
  for (int it = tid; it < 32 * 128; it += 256) {
    int rr = it >> 7, c4 = it & 127;
    float4 v = *(const float4*)(blur + (size_t)(row0 + rr) * WW + col0 + c4 * 4);
    int g = ((row0 + rr) << 10) + (col0 >> 2) + c4;   // global 4-px group
    u64 b0 = __ballot(v.x > tf);
    u64 b1 = __ballot(v.y > tf);
    u64 b2 = __ballot(v.z > tf);
    u64 b3 = __ballot(v.w > tf);
    if ((lane & 15) == 0) {
      int sh = lane;             // 0,16,32,48
      u64 w = spread4(b0 >> sh) | (spread4(b1 >> sh) << 1)
            | (spread4(b2 >> sh) << 2) | (spread4(b3 >> sh) << 3);
      int base_word = ((g - lane) * 4) >> 6;
      pk[base_word + (lane >> 4)] = w;
    }
  }
}

// ---------------------------------------------------------------------------
// 5) FUSED morphology: dilate then erode (De Morgan) + unpack, one kernel.
//    16-row x 16-word tiles (1024 blocks). OOB = 0 (clipped window);
//    erode complement only inside the valid frame (old erode's OOB rule).
// ---------------------------------------------------------------------------
__global__ void __launch_bounds__(256)
morph_kernel(const u64* __restrict__ in, float* __restrict__ out) {
  __shared__ u64 pkin[24][20];   // rows R0-4..R0+19, words W0-2..W0+17
  __shared__ u64 hA[24][20];
  __shared__ u64 nD[20][20];
  __shared__ u64 hB[20][20];
  int bx = blockIdx.x & 3;
  int by = blockIdx.x >> 2;
  int R0 = by * 16, W0 = bx * 16;
  int tid = threadIdx.x;
  for (int it = tid; it < 24 * 20; it += 256) {
    int i = it / 20, j = it % 20;
    int gy = R0 - 4 + i, gx = W0 - 2 + j;
    u64 m = 0;
    if ((unsigned)gy < (unsigned)HH && (unsigned)gx < (unsigned)WPR)
      m = in[gy * WPR + gx];
    pkin[i][j] = m;
  }
  __syncthreads();
  for (int it = tid; it < 24 * 18; it += 256) {
    int i = it / 18, j = 1 + it % 18;
    u64 m = pkin[i][j], l = pkin[i][j - 1], r = pkin[i][j + 1];
    hA[i][j] = m | (m << 1) | (m << 2) | (m >> 1) | (m >> 2)
                 | (l >> 62) | (l >> 63) | (r << 62) | (r << 63);
  }
  __syncthreads();
  for (int it = tid; it < 20 * 18; it += 256) {
    int i = it / 18, j = 1 + it % 18;
    u64 v = hA[i][j] | hA[i + 1][j] | hA[i + 2][j] | hA[i + 3][j] | hA[i + 4][j];
    int gy = R0 - 2 + i, gx = W0 - 2 + j;
    nD[i][j] = ((unsigned)gy < (unsigned)HH && (unsigned)gx < (unsigned)WPR)
                   ? ~v : 0ull;
  }
  __syncthreads();
  for (int it = tid; it < 20 * 16; it += 256) {
    int i = it / 16, j = 2 + it % 16;
    u64 m = nD[i][j], l = nD[i][j - 1], r = nD[i][j + 1];
    hB[i][j] = m | (m << 1) | (m << 2) | (m >> 1) | (m >> 2)
                 | (l >> 62) | (l >> 63) | (r << 62) | (r << 63);
  }
  __syncthreads();
  int colbase = W0 * 64;
  for (int it = tid; it < 16 * 256; it += 256) {
    int o = it >> 8;           // output row 0..15
    int px0 = (it & 255) * 4;  // col within the 1024-px tile
    int j = 2 + (px0 >> 6);
    u64 v = hB[o][j] | hB[o + 1][j] | hB[o + 2][j] | hB[o + 3][j] | hB[o + 4][j];
    int sh = px0 & 63;
    float4 ov;
    ov.x = (float)(1 - (int)((v >> (sh + 0)) & 1ull));
    ov.y = (float)(1 - (int)((v >> (sh + 1)) & 1ull));
    ov.z = (float)(1 - (int)((v >> (sh + 2)) & 1ull));
    ov.w = (float)(1 - (int)((v >> (sh + 3)) & 1ull));
    *(float4*)(out + (size_t)(R0 + o) * WW + colbase + px0) = ov;
  }
}

// ---------------------------------------------------------------------------
extern "C" void kernel_launch(void* const* d_in, const int* in_sizes, int n_in,
                              void* d_out, int out_size, void* d_ws, size_t ws_size,
                              hipStream_t stream) {
  const float* x = (const float*)d_in[0];
  if (n_in > 1 && in_sizes[0] != NPIX) x = (const float*)d_in[1];
  float* out = (float*)d_out;
  char* ws = (char*)d_ws;

  // workspace layout — hist, bandcnt, done are contiguous: one memset.
  const size_t OFF_HIST = 0;          // 2,097,152
  const size_t OFF_BCNT = 2097152;    // 256
  const size_t OFF_DONE = 2097408;    // 4 (+4 pad)
  const size_t OFF_TH   = 2097416;    // 256
  const size_t OFF_PKA  = 2097672;    // 2,097,152 (8-aligned)
  const size_t OFF_BINS = 6291968;    // 1,024
  const size_t OFF_VHL  = 6292992;    // 512
  const size_t OFF_BAND = 6293504;    // 1,048,576
  const size_t OFF_BLUR = 8388608;    // 64 MB blur image
  const size_t WS_NEED  = OFF_BLUR + (size_t)NPIX * sizeof(float);  // 72 MB
  uint32_t* hist    = (uint32_t*)(ws + OFF_HIST);
  uint32_t* bandcnt = (uint32_t*)(ws + OFF_BCNT);
  uint32_t* done    = (uint32_t*)(ws + OFF_DONE);
  float*    th      = (float*)(ws + OFF_TH);
  u64*      PKA     = (u64*)(ws + OFF_PKA);
  int4*     bins4   = (int4*)(ws + OFF_BINS);
  float2*   vhl     = (float2*)(ws + OFF_VHL);
  float*    band    = (float*)(ws + OFF_BAND);

  float* blurred = (ws_size >= WS_NEED) ? (float*)(ws + OFF_BLUR) : out;

  const int TPB = 256;

  // one memset covers hist (2 MB) + bandcnt (256 B) + done (4 B)
  hipMemsetAsync(hist, 0,
                 (size_t)NFRAG * NBINS * sizeof(uint32_t) + NFRAG * sizeof(uint32_t) + 8,
                 stream);
  blur_hist_kernel<<<2048, 512, 0, stream>>>(x, blurred, hist);
  findcrit_gather_kernel<<<1024, TPB, 0, stream>>>(blurred, hist, bins4, band, bandcnt);
  select_walk_kernel<<<NFRAG, TPB, 0, stream>>>(band, bandcnt, bins4, vhl, done, th);
  mask_pack_kernel<<<1024, TPB, 0, stream>>>(blurred, th, PKA);
  morph_kernel<<<1024, TPB, 0, stream>>>(PKA, out);
}

// Round 15
// 253.447 us; speedup vs baseline: 1.0489x; 1.0489x over previous
//
#include <hip/hip_runtime.h>
#include <stdint.h>

#define HH 4096
#define WW 4096
#define NPIX (HH * WW)
#define NBINS 8192
#define NFRAG 64
#define FRAG_PIX (512 * 512)   // 2^18
#define WPR 64                 // u64 words per row (4096/64)
#define NWORDS (HH * WPR)      // 262144
#define CAP 4096               // per-fragment critical-band capacity
#define LCAP 2048              // per-block LDS match buffer

// Reference stop conditions (integer-exact):
//   phase0 stop: cnt >= 31458 <=> th < V_HI,  V_HI = v_sorted[230686]
//   phase1 stop: cnt <= 20971 <=> th >= V_LO, V_LO = v_sorted[241172]
#define RANK_HI 230686u
#define RANK_LO 241172u

typedef unsigned long long u64;

__device__ __forceinline__ int bin_of(float v) {
  int b = (int)(v * 8192.0f);   // monotone f32 map
  if (b < 0) b = 0;
  if (b > NBINS - 1) b = NBINS - 1;
  return b;
}

// spread 16 bits so bit i lands at position 4i
__device__ __forceinline__ u64 spread4(u64 x) {
  x &= 0xFFFFull;
  x = (x | (x << 24)) & 0x000000FF000000FFull;
  x = (x | (x << 12)) & 0x000F000F000F000Full;
  x = (x | (x << 6))  & 0x0303030303030303ull;
  x = (x | (x << 3))  & 0x1111111111111111ull;
  return x;
}

// ---------------------------------------------------------------------------
// VERIFIED bit-exact blur tree (numpy pairwise_sum n=25 over materialized
// (windows*k), row-major taps, OOB -> exact 0). DO NOT TOUCH.
// ---------------------------------------------------------------------------
__device__ __forceinline__ float blur_tree(const float rowbuf[5][8], int e) {
  const float K = (float)(1.0 / 25.0);
  float p[25];
#pragma unroll
  for (int i = 0; i < 25; ++i) {
    p[i] = __fmul_rn(rowbuf[i / 5][e + (i % 5)], K);
  }
  float r0 = __fadd_rn(__fadd_rn(p[0], p[8]),  p[16]);
  float r1 = __fadd_rn(__fadd_rn(p[1], p[9]),  p[17]);
  float r2 = __fadd_rn(__fadd_rn(p[2], p[10]), p[18]);
  float r3 = __fadd_rn(__fadd_rn(p[3], p[11]), p[19]);
  float r4 = __fadd_rn(__fadd_rn(p[4], p[12]), p[20]);
  float r5 = __fadd_rn(__fadd_rn(p[5], p[13]), p[21]);
  float r6 = __fadd_rn(__fadd_rn(p[6], p[14]), p[22]);
  float r7 = __fadd_rn(__fadd_rn(p[7], p[15]), p[23]);
  float res = __fadd_rn(
      __fadd_rn(__fadd_rn(r0, r1), __fadd_rn(r2, r3)),
      __fadd_rn(__fadd_rn(r4, r5), __fadd_rn(r6, r7)));
  return __fadd_rn(res, p[24]);
}

// ---------------------------------------------------------------------------
// 1) FUSED blur + per-fragment LDS histogram (staggered flush).
//    R7-proven config: 4x4 patch/thread, 512 threads, 1024 blocks.
// ---------------------------------------------------------------------------
__global__ void __launch_bounds__(512)
blur_hist_kernel(const float* __restrict__ x,
                 float* __restrict__ out,
                 uint32_t* __restrict__ hist) {
  __shared__ uint32_t lh[NBINS];
  int tid = threadIdx.x;
  for (int i = tid; i < NBINS; i += 512) lh[i] = 0;
  __syncthreads();
  int f = blockIdx.x >> 4;
  int s = blockIdx.x & 15;
  int row0 = (f >> 3) * 512 + s * 32;
  int col0 = (f & 7) * 512;
  // 8 patch-rows x 128 patch-cols per 32x512 slice; 512 threads -> 2 iters
  for (int it = tid; it < 8 * 128; it += 512) {
    int pr = it >> 7;          // patch row 0..7
    int c4 = it & 127;         // patch col 0..127
    int py = row0 + pr * 4;
    int px = col0 + c4 * 4;
    float rb[8][8];
    bool interior = (px >= 2) && (px + 5 < WW);
#pragma unroll
    for (int r = 0; r < 8; ++r) {
      int yy = py - 2 + r;
      if ((unsigned)yy >= (unsigned)HH) {
#pragma unroll
        for (int j = 0; j < 8; ++j) rb[r][j] = 0.0f;
      } else if (interior) {
        const float* rp = x + (size_t)yy * WW + px;
        float2 L = *(const float2*)(rp - 2);
        float4 M = *(const float4*)(rp);
        float2 R = *(const float2*)(rp + 4);
        rb[r][0] = L.x; rb[r][1] = L.y;
        rb[r][2] = M.x; rb[r][3] = M.y;
        rb[r][4] = M.z; rb[r][5] = M.w;
        rb[r][6] = R.x; rb[r][7] = R.y;
      } else {
#pragma unroll
        for (int j = 0; j < 8; ++j) {
          int xx = px - 2 + j;
          rb[r][j] = ((unsigned)xx < (unsigned)WW) ? x[(size_t)yy * WW + xx] : 0.0f;
        }
      }
    }
#pragma unroll
    for (int orow = 0; orow < 4; ++orow) {
      float4 res;
      res.x = blur_tree(rb + orow, 0);
      res.y = blur_tree(rb + orow, 1);
      res.z = blur_tree(rb + orow, 2);
      res.w = blur_tree(rb + orow, 3);
      *(float4*)(out + (size_t)(py + orow) * WW + px) = res;
      atomicAdd(&lh[bin_of(res.x)], 1u);
      atomicAdd(&lh[bin_of(res.y)], 1u);
      atomicAdd(&lh[bin_of(res.z)], 1u);
      atomicAdd(&lh[bin_of(res.w)], 1u);
    }
  }
  __syncthreads();
  uint32_t* hf = hist + f * NBINS;
  int start = ((s << 9) + tid) & (NBINS - 1);   // sibling-staggered sweep
  for (int ii = 0; ii < NBINS; ii += 512) {
    int i = (start + ii) & (NBINS - 1);
    uint32_t c = lh[i];
    if (c) atomicAdd(&hf[i], c);
  }
}

// ---------------------------------------------------------------------------
// 2) find critical buckets + local ranks. bins4[f] = (bhi, blo, khi, klo).
// ---------------------------------------------------------------------------
__global__ void findcrit_kernel(const uint32_t* __restrict__ hist,
                                int4* __restrict__ bins4) {
  __shared__ uint32_t segsum[256];
  __shared__ uint32_t segoff[256];
  __shared__ int4 result;
  int f = blockIdx.x;
  int tid = threadIdx.x;
  const uint32_t* hf = hist + f * NBINS;
  int base = tid * 32;
  uint32_t h32[32];
  uint32_t s = 0;
  for (int i = 0; i < 32; ++i) { h32[i] = hf[base + i]; s += h32[i]; }
  segsum[tid] = s;
  __syncthreads();
  if (tid == 0) {
    uint32_t a = 0;
    for (int i = 0; i < 256; ++i) { segoff[i] = a; a += segsum[i]; }
  }
  __syncthreads();
  uint32_t st = segoff[tid];
  uint32_t en = st + segsum[tid];
  if (st <= RANK_HI && RANK_HI < en) {
    uint32_t a = st;
    for (int i = 0; i < 32; ++i) {
      uint32_t nx = a + h32[i];
      if (RANK_HI < nx) { result.x = base + i; result.z = (int)(RANK_HI - a); break; }
      a = nx;
    }
  }
  if (st <= RANK_LO && RANK_LO < en) {
    uint32_t a = st;
    for (int i = 0; i < 32; ++i) {
      uint32_t nx = a + h32[i];
      if (RANK_LO < nx) { result.y = base + i; result.w = (int)(RANK_LO - a); break; }
      a = nx;
    }
  }
  __syncthreads();
  if (tid == 0) bins4[f] = result;
}

// ---------------------------------------------------------------------------
// 3) gather — atomic-privatized (R6-verified). LDS collect + one global
//    atomicAdd per block. Order-independent select makes this bit-exact.
// ---------------------------------------------------------------------------
__global__ void __launch_bounds__(256)
gather_kernel(const float* __restrict__ blur,
              const int4* __restrict__ bins4,
              float* __restrict__ band,
              uint32_t* __restrict__ bandcnt) {
  __shared__ float lval[LCAP];
  __shared__ uint32_t lcnt;
  __shared__ uint32_t gbase;
  int f = blockIdx.x >> 4;
  int s = blockIdx.x & 15;
  int tid = threadIdx.x;
  if (tid == 0) lcnt = 0;
  __syncthreads();
  int row0 = (f >> 3) * 512 + s * 32;
  int col0 = (f & 7) * 512;
  int4 info = bins4[f];
  for (int it = tid; it < 32 * 128; it += 256) {
    int rr = it >> 7, c4 = it & 127;
    float4 v = *(const float4*)(blur + (size_t)(row0 + rr) * WW + col0 + c4 * 4);
    float vv[4] = {v.x, v.y, v.z, v.w};
#pragma unroll
    for (int e = 0; e < 4; ++e) {
      int b = bin_of(vv[e]);
      if (b == info.x || b == info.y) {
        uint32_t p = atomicAdd(&lcnt, 1u);
        if (p < LCAP) lval[p] = vv[e];
        else {   // overflow fallback (never for expected data)
          uint32_t pos = atomicAdd(&bandcnt[f], 1u);
          if (pos < CAP) band[(size_t)f * CAP + pos] = vv[e];
        }
      }
    }
  }
  __syncthreads();
  uint32_t n = lcnt < LCAP ? lcnt : LCAP;
  if (tid == 0) gbase = atomicAdd(&bandcnt[f], n);
  __syncthreads();
  uint32_t base = gbase;
  for (uint32_t i = tid; i < n; i += 256) {
    uint32_t pos = base + i;
    if (pos < CAP) band[(size_t)f * CAP + pos] = lval[i];
  }
}

// ---------------------------------------------------------------------------
// 4) exact order-statistic selection within the critical buckets
// ---------------------------------------------------------------------------
__global__ void select_kernel(const float* __restrict__ band,
                              const uint32_t* __restrict__ bandcnt,
                              const int4* __restrict__ bins4,
                              float2* __restrict__ vhl) {
  __shared__ float wv[CAP];
  __shared__ float res[2];
  int f = blockIdx.x;
  int tid = threadIdx.x;
  int n = (int)bandcnt[f];
  if (n > CAP) n = CAP;
  for (int i = tid; i < n; i += 256) wv[i] = band[(size_t)f * CAP + i];
  __syncthreads();
  int4 info = bins4[f];
#pragma unroll
  for (int sel = 0; sel < 2; ++sel) {
    int tb = sel ? info.y : info.x;
    int k  = sel ? info.w : info.z;
    for (int i = tid; i < n; i += 256) {
      float w = wv[i];
      if (bin_of(w) != tb) continue;
      int less = 0, leq = 0;
      for (int j = 0; j < n; ++j) {
        float u = wv[j];
        if (bin_of(u) == tb) {
          less += (u < w) ? 1 : 0;
          leq  += (u <= w) ? 1 : 0;
        }
      }
      if (less <= k && k < leq) res[sel] = w;   // unique value; benign race
    }
  }
  __syncthreads();
  if (tid == 0) vhl[f] = make_float2(res[0], res[1]);
}

// ---------------------------------------------------------------------------
// 5) threshold walk — branchless predicated steps (16 per exit check).
// ---------------------------------------------------------------------------
__global__ void walk_kernel(const float2* __restrict__ vhl, float* __restrict__ th_out) {
  int lane = threadIdx.x;
  float2 mine = vhl[lane];   // lane f holds fragment f's (V_HI, V_LO)
  float th = 0.5f;           // TH1_INIT
  for (int f = 0; f < NFRAG; ++f) {
    float VH = __shfl(mine.x, f);
    float VL = __shfl(mine.y, f);
    // phase 0: while th >= VH: th -= 0.0005
    while (th >= VH) {
#pragma unroll
      for (int i = 0; i < 16; ++i) {
        float t2 = __fadd_rn(th, -0.0005f);
        th = (th >= VH) ? t2 : th;
      }
    }
    // phase 1: while th < VL: th += 0.0005
    while (th < VL) {
#pragma unroll
      for (int i = 0; i < 16; ++i) {
        float t2 = __fadd_rn(th, 0.0005f);
        th = (th < VL) ? t2 : th;
      }
    }
    if (lane == 0) th_out[f] = th;
  }
}

// ---------------------------------------------------------------------------
// 6) mask + bit-pack — fragment-slice blocks; th[f] wave-uniform scalar.
// ---------------------------------------------------------------------------
__global__ void __launch_bounds__(256)
mask_pack_kernel(const float* __restrict__ blur,
                 const float* __restrict__ th,
                 u64* __restrict__ pk) {
  int f = blockIdx.x >> 4;
  int s = blockIdx.x & 15;
  int tid = threadIdx.x;
  int lane = tid & 63;
  int row0 = (f >> 3) * 512 + s * 32;
  int col0 = (f & 7) * 512;
  float tf = th[f];
  for (int it = tid; it < 32 * 128; it += 256) {
    int rr = it >> 7, c4 = it & 127;
    float4 v = *(const float4*)(blur + (size_t)(row0 + rr) * WW + col0 + c4 * 4);
    int g = ((row0 + rr) << 10) + (col0 >> 2) + c4;   // global 4-px group
    u64 b0 = __ballot(v.x > tf);
    u64 b1 = __ballot(v.y > tf);
    u64 b2 = __ballot(v.z > tf);
    u64 b3 = __ballot(v.w > tf);
    if ((lane & 15) == 0) {
      int sh = lane;             // 0,16,32,48
      u64 w = spread4(b0 >> sh) | (spread4(b1 >> sh) << 1)
            | (spread4(b2 >> sh) << 2) | (spread4(b3 >> sh) << 3);
      int base_word = ((g - lane) * 4) >> 6;
      pk[base_word + (lane >> 4)] = w;
    }
  }
}

// ---------------------------------------------------------------------------
// 7) FUSED morphology: dilate then erode (De Morgan) + unpack, one kernel.
//    16-row x 16-word tiles (1024 blocks). OOB = 0 (clipped window);
//    erode complement only inside the valid frame (old erode's OOB rule).
// ---------------------------------------------------------------------------
__global__ void __launch_bounds__(256)
morph_kernel(const u64* __restrict__ in, float* __restrict__ out) {
  __shared__ u64 pkin[24][20];   // rows R0-4..R0+19, words W0-2..W0+17
  __shared__ u64 hA[24][20];
  __shared__ u64 nD[20][20];
  __shared__ u64 hB[20][20];
  int bx = blockIdx.x & 3;
  int by = blockIdx.x >> 2;
  int R0 = by * 16, W0 = bx * 16;
  int tid = threadIdx.x;
  for (int it = tid; it < 24 * 20; it += 256) {
    int i = it / 20, j = it % 20;
    int gy = R0 - 4 + i, gx = W0 - 2 + j;
    u64 m = 0;
    if ((unsigned)gy < (unsigned)HH && (unsigned)gx < (unsigned)WPR)
      m = in[gy * WPR + gx];
    pkin[i][j] = m;
  }
  __syncthreads();
  for (int it = tid; it < 24 * 18; it += 256) {
    int i = it / 18, j = 1 + it % 18;
    u64 m = pkin[i][j], l = pkin[i][j - 1], r = pkin[i][j + 1];
    hA[i][j] = m | (m << 1) | (m << 2) | (m >> 1) | (m >> 2)
                 | (l >> 62) | (l >> 63) | (r << 62) | (r << 63);
  }
  __syncthreads();
  for (int it = tid; it < 20 * 18; it += 256) {
    int i = it / 18, j = 1 + it % 18;
    u64 v = hA[i][j] | hA[i + 1][j] | hA[i + 2][j] | hA[i + 3][j] | hA[i + 4][j];
    int gy = R0 - 2 + i, gx = W0 - 2 + j;
    nD[i][j] = ((unsigned)gy < (unsigned)HH && (unsigned)gx < (unsigned)WPR)
                   ? ~v : 0ull;
  }
  __syncthreads();
  for (int it = tid; it < 20 * 16; it += 256) {
    int i = it / 16, j = 2 + it % 16;
    u64 m = nD[i][j], l = nD[i][j - 1], r = nD[i][j + 1];
    hB[i][j] = m | (m << 1) | (m << 2) | (m >> 1) | (m >> 2)
                 | (l >> 62) | (l >> 63) | (r << 62) | (r << 63);
  }
  __syncthreads();
  int colbase = W0 * 64;
  for (int it = tid; it < 16 * 256; it += 256) {
    int o = it >> 8;           // output row 0..15
    int px0 = (it & 255) * 4;  // col within the 1024-px tile
    int j = 2 + (px0 >> 6);
    u64 v = hB[o][j] | hB[o + 1][j] | hB[o + 2][j] | hB[o + 3][j] | hB[o + 4][j];
    int sh = px0 & 63;
    float4 ov;
    ov.x = (float)(1 - (int)((v >> (sh + 0)) & 1ull));
    ov.y = (float)(1 - (int)((v >> (sh + 1)) & 1ull));
    ov.z = (float)(1 - (int)((v >> (sh + 2)) & 1ull));
    ov.w = (float)(1 - (int)((v >> (sh + 3)) & 1ull));
    *(float4*)(out + (size_t)(R0 + o) * WW + colbase + px0) = ov;
  }
}

// ---------------------------------------------------------------------------
extern "C" void kernel_launch(void* const* d_in, const int* in_sizes, int n_in,
                              void* d_out, int out_size, void* d_ws, size_t ws_size,
                              hipStream_t stream) {
  const float* x = (const float*)d_in[0];
  if (n_in > 1 && in_sizes[0] != NPIX) x = (const float*)d_in[1];
  float* out = (float*)d_out;
  char* ws = (char*)d_ws;

  const size_t OFF_HIST = 0;          // 2,097,152
  const size_t OFF_BCNT = 2097152;    // 256
  const size_t OFF_TH   = 2097408;    // 256
  const size_t OFF_PKA  = 2097664;    // 2,097,152
  const size_t OFF_BINS = 6291968;    // 1,024
  const size_t OFF_VHL  = 6292992;    // 512
  const size_t OFF_BAND = 6293504;    // 1,048,576
  const size_t OFF_BLUR = 8388608;    // 64 MB blur image
  const size_t WS_NEED  = OFF_BLUR + (size_t)NPIX * sizeof(float);  // 72 MB
  uint32_t* hist    = (uint32_t*)(ws + OFF_HIST);
  uint32_t* bandcnt = (uint32_t*)(ws + OFF_BCNT);
  float*    th      = (float*)(ws + OFF_TH);
  u64*      PKA     = (u64*)(ws + OFF_PKA);
  int4*     bins4   = (int4*)(ws + OFF_BINS);
  float2*   vhl     = (float2*)(ws + OFF_VHL);
  float*    band    = (float*)(ws + OFF_BAND);

  float* blurred = (ws_size >= WS_NEED) ? (float*)(ws + OFF_BLUR) : out;

  const int TPB = 256;

  // one memset covers hist (2 MB) + bandcnt (256 B), adjacent in ws
  hipMemsetAsync(hist, 0, (size_t)NFRAG * NBINS * sizeof(uint32_t) + NFRAG * sizeof(uint32_t), stream);
  blur_hist_kernel<<<1024, 512, 0, stream>>>(x, blurred, hist);
  findcrit_kernel<<<NFRAG, TPB, 0, stream>>>(hist, bins4);
  gather_kernel<<<1024, TPB, 0, stream>>>(blurred, bins4, band, bandcnt);
  select_kernel<<<NFRAG, TPB, 0, stream>>>(band, bandcnt, bins4, vhl);
  walk_kernel<<<1, 64, 0, stream>>>(vhl, th);
  mask_pack_kernel<<<1024, TPB, 0, stream>>>(blurred, th, PKA);
  morph_kernel<<<1024, TPB, 0, stream>>>(PKA, out);
}